// Round 1
// baseline (417.820 us; speedup 1.0000x reference)
//
#include <hip/hip_runtime.h>

// TrellisLinear: out = (x * su) @ (grid[codes] * scales * sv)
// M=512, K=8192, N=8192, GROUP=128 (shapes derived from in_sizes at launch).
//
// Round 1: split pipeline.
//   1) convert_x_su : x'[m][k] = bf16(x[m][k] * su[k])           (ws)
//   2) dequant_wt   : Wt[n][k] = bf16(grid[code] * scales[g][n] * sv[n])  (ws, K-major)
//   3) gemm_xw      : C[m][n] = sum_k x'[m][k] * Wt[n][k]        (MFMA bf16, f32 out)

typedef __attribute__((ext_vector_type(8))) short short8;
typedef __attribute__((ext_vector_type(4))) float f32x4;

// RNE float -> bf16 bits (finite inputs only).
__device__ __forceinline__ unsigned short f2bf(float f) {
  unsigned int u = __builtin_bit_cast(unsigned int, f);
  u += 0x7FFFu + ((u >> 16) & 1u);
  return (unsigned short)(u >> 16);
}

// async global -> LDS, 16B per lane. LDS dest must be wave-uniform base + lane*16.
__device__ __forceinline__ void gld16(const void* g, void* l) {
  __builtin_amdgcn_global_load_lds(
      (__attribute__((address_space(1))) void*)(g),
      (__attribute__((address_space(3))) void*)(l),
      16, 0, 0);
}

// ---------------------------------------------------------------------------
// Kernel 1: x' = bf16(x * su), row-major [M][K]
// grid: (K/2048, M), 256 threads, 8 elems/thread
__global__ __launch_bounds__(256) void convert_x_su(
    const float* __restrict__ x, const float* __restrict__ su,
    unsigned short* __restrict__ xp, int K) {
  int k = blockIdx.x * 2048 + threadIdx.x * 8;
  size_t i = (size_t)blockIdx.y * K + k;
  float4 x0 = *(const float4*)(x + i);
  float4 x1 = *(const float4*)(x + i + 4);
  float4 s0 = *(const float4*)(su + k);
  float4 s1 = *(const float4*)(su + k + 4);
  unsigned int r0 = f2bf(x0.x * s0.x) | ((unsigned int)f2bf(x0.y * s0.y) << 16);
  unsigned int r1 = f2bf(x0.z * s0.z) | ((unsigned int)f2bf(x0.w * s0.w) << 16);
  unsigned int r2 = f2bf(x1.x * s1.x) | ((unsigned int)f2bf(x1.y * s1.y) << 16);
  unsigned int r3 = f2bf(x1.z * s1.z) | ((unsigned int)f2bf(x1.w * s1.w) << 16);
  uint4 o; o.x = r0; o.y = r1; o.z = r2; o.w = r3;
  *(uint4*)(xp + i) = o;
}

// ---------------------------------------------------------------------------
// Kernel 2: Wt[n][k] (K-major / B^T) via LDS transpose.
// Tile: 64 n x 64 k per block, 256 threads. grid: (N/64, K/64).
__global__ __launch_bounds__(256) void dequant_wt(
    const int* __restrict__ packed, const float* __restrict__ gridv,
    const float* __restrict__ scales, const float* __restrict__ sv,
    unsigned short* __restrict__ Wt, int K, int N) {
  __shared__ float sG[16];
  __shared__ float sA[64];
  __shared__ unsigned short sW[64][66];  // [n][k] + pad(2) -> 33-word rows, 2-way max conflicts

  int t = threadIdx.x;
  int n0 = blockIdx.x * 64;
  int k0 = blockIdx.y * 64;
  int g = k0 >> 7;  // GROUP=128; 64-k tile stays inside one group
  if (t < 16) sG[t] = gridv[t];
  if (t < 64) sA[t] = scales[(size_t)g * N + n0 + t] * sv[n0 + t];
  __syncthreads();

  int n2l = t & 31;   // local packed-column (covers n = 2*n2l, 2*n2l+1)
  int kg  = t >> 5;   // 0..7, each handles 8 k-rows
  const int* psrc = packed + (size_t)(k0 + kg * 8) * (N >> 1) + (n0 >> 1) + n2l;
  float alo = sA[2 * n2l], ahi = sA[2 * n2l + 1];

  int pv[8];
#pragma unroll
  for (int j = 0; j < 8; ++j) pv[j] = psrc[(size_t)j * (N >> 1)];
#pragma unroll
  for (int j = 0; j < 8; ++j) {
    int kl = kg * 8 + j;
    sW[2 * n2l][kl]     = f2bf(sG[pv[j] & 15] * alo);
    sW[2 * n2l + 1][kl] = f2bf(sG[(pv[j] >> 4) & 15] * ahi);
  }
  __syncthreads();

  // Write out coalesced: 2 passes, 16B per thread per pass.
  const unsigned int* wrow = (const unsigned int*)&sW[0][0];
#pragma unroll
  for (int p = 0; p < 2; ++p) {
    int nl = p * 32 + (t >> 3);
    int c  = (t & 7) * 8;  // k offset (ushorts)
    const unsigned int* rp = wrow + nl * 33 + (c >> 1);
    uint4 v; v.x = rp[0]; v.y = rp[1]; v.z = rp[2]; v.w = rp[3];
    *(uint4*)(Wt + (size_t)(n0 + nl) * K + k0 + c) = v;
  }
}

// ---------------------------------------------------------------------------
// Kernel 3: C = x' @ Wt^T (both operands K-major). m97-style structure.
#define BM 128
#define BN 64
#define BK 32

__global__ __launch_bounds__(256, 2) void gemm_xw(
    const unsigned short* __restrict__ A,  // [M][K] bf16 bits
    const unsigned short* __restrict__ B,  // [N][K] bf16 bits
    float* __restrict__ C, int M, int N, int K) {
  __shared__ unsigned short As[BM * BK];  // 8 KB
  __shared__ unsigned short Bs[BN * BK];  // 4 KB

  int t = threadIdx.x;
  int l = t & 63;
  int w = t >> 6;          // wave 0..3
  int wr = w >> 1;         // 0..1 : M half
  int wc = w & 1;          // 0..1 : N half (wave tile 64x32)
  size_t m0 = (size_t)blockIdx.y * BM;
  size_t n0 = (size_t)blockIdx.x * BN;
  const unsigned short* Ag = A + m0 * K;
  const unsigned short* Bg = B + n0 * K;

  int srow = t >> 2;        // staging row 0..63
  int sc   = (t & 3) * 8;   // staging 16B chunk (ushorts)
  int lr = l & 15;
  int lk = (l >> 4) * 8;

  f32x4 acc[4][2] = {};

  for (int k0 = 0; k0 < K; k0 += BK) {
    gld16(Ag + (size_t)srow * K + k0 + sc,        &As[srow * BK + sc]);
    gld16(Ag + (size_t)(srow + 64) * K + k0 + sc, &As[(srow + 64) * BK + sc]);
    gld16(Bg + (size_t)srow * K + k0 + sc,        &Bs[srow * BK + sc]);
    __syncthreads();

    short8 a[4], b[2];
#pragma unroll
    for (int i = 0; i < 4; ++i)
      a[i] = *(const short8*)&As[(wr * 64 + i * 16 + lr) * BK + lk];
#pragma unroll
    for (int j = 0; j < 2; ++j)
      b[j] = *(const short8*)&Bs[(wc * 32 + j * 16 + lr) * BK + lk];
#pragma unroll
    for (int i = 0; i < 4; ++i)
#pragma unroll
      for (int j = 0; j < 2; ++j)
        acc[i][j] = __builtin_amdgcn_mfma_f32_16x16x32_bf16(a[i], b[j], acc[i][j], 0, 0, 0);
    __syncthreads();
  }

  // Epilogue: D layout col=lane&15, row=(lane>>4)*4+r (m89/m91-verified).
  int lq = l >> 4;
#pragma unroll
  for (int i = 0; i < 4; ++i)
#pragma unroll
    for (int j = 0; j < 2; ++j) {
      size_t row = m0 + wr * 64 + i * 16 + lq * 4;
      size_t col = n0 + wc * 32 + j * 16 + lr;
#pragma unroll
      for (int r = 0; r < 4; ++r)
        C[(row + r) * N + col] = acc[i][j][r];
    }
}

// ---------------------------------------------------------------------------
extern "C" void kernel_launch(void* const* d_in, const int* in_sizes, int n_in,
                              void* d_out, int out_size, void* d_ws, size_t ws_size,
                              hipStream_t stream) {
  const float* x      = (const float*)d_in[0];
  const int*   packed = (const int*)d_in[1];
  const float* gridv  = (const float*)d_in[2];
  const float* scales = (const float*)d_in[3];
  const float* su     = (const float*)d_in[4];
  const float* sv     = (const float*)d_in[5];
  float* out = (float*)d_out;

  int K = in_sizes[4];          // su
  int N = in_sizes[5];          // sv
  int M = in_sizes[0] / K;      // x = M*K

  // ws layout: x' bf16 [M][K] (8 MB) then Wt bf16 [N][K] (128 MB). Needs ~136 MB.
  unsigned short* xp = (unsigned short*)d_ws;
  unsigned short* Wt = xp + (size_t)M * K;

  convert_x_su<<<dim3(K / 2048, M), 256, 0, stream>>>(x, su, xp, K);
  dequant_wt<<<dim3(N / 64, K / 64), 256, 0, stream>>>(packed, gridv, scales, sv, Wt, K, N);
  gemm_xw<<<dim3(N / BN, M / BM), 256, 0, stream>>>(xp, Wt, out, M, N, K);
}

// Round 2
// 363.536 us; speedup vs baseline: 1.1493x; 1.1493x over previous
//
#include <hip/hip_runtime.h>

// TrellisLinear: out = (x * su) @ (grid[codes] * scales * sv)
// M=512, K=8192, N=8192, GROUP=128.
// Round 2: faster dequant (128x128 tiles, b128 LDS, swizzle) +
//          gemm BK=64, wave 64x64, split-K=4 (atomics), LDS XOR swizzle
//          via pre-swizzled global_load_lds source.

typedef __attribute__((ext_vector_type(8))) short short8;
typedef __attribute__((ext_vector_type(4))) float f32x4;

__device__ __forceinline__ unsigned short f2bf(float f) {
  unsigned int u = __builtin_bit_cast(unsigned int, f);
  u += 0x7FFFu + ((u >> 16) & 1u);
  return (unsigned short)(u >> 16);
}

__device__ __forceinline__ void gld16(const void* g, void* l) {
  __builtin_amdgcn_global_load_lds(
      (__attribute__((address_space(1))) void*)(g),
      (__attribute__((address_space(3))) void*)(l), 16, 0, 0);
}

// ---------------------------------------------------------------------------
// zero-init d_out (poisoned 0xAA before every timed call)
__global__ __launch_bounds__(256) void zero_out(float4* __restrict__ p, int n4) {
  int i = blockIdx.x * 256 + threadIdx.x;
  int stride = gridDim.x * 256;
  for (; i < n4; i += stride) p[i] = float4{0.f, 0.f, 0.f, 0.f};
}

// ---------------------------------------------------------------------------
// x' = bf16(x * su), row-major [M][K]. grid: (K/2048, M), 256 thr.
__global__ __launch_bounds__(256) void convert_x_su(
    const float* __restrict__ x, const float* __restrict__ su,
    unsigned short* __restrict__ xp, int K) {
  int k = blockIdx.x * 2048 + threadIdx.x * 8;
  size_t i = (size_t)blockIdx.y * K + k;
  float4 x0 = *(const float4*)(x + i);
  float4 x1 = *(const float4*)(x + i + 4);
  float4 s0 = *(const float4*)(su + k);
  float4 s1 = *(const float4*)(su + k + 4);
  unsigned int r0 = f2bf(x0.x * s0.x) | ((unsigned int)f2bf(x0.y * s0.y) << 16);
  unsigned int r1 = f2bf(x0.z * s0.z) | ((unsigned int)f2bf(x0.w * s0.w) << 16);
  unsigned int r2 = f2bf(x1.x * s1.x) | ((unsigned int)f2bf(x1.y * s1.y) << 16);
  unsigned int r3 = f2bf(x1.z * s1.z) | ((unsigned int)f2bf(x1.w * s1.w) << 16);
  uint4 o; o.x = r0; o.y = r1; o.z = r2; o.w = r3;
  *(uint4*)(xp + i) = o;
}

// ---------------------------------------------------------------------------
// Wt[n][k] (K-major) dequant+transpose. Tile 128n x 128k, 256 thr.
// grid: (N/128, K/128). K-tile == GROUP so one scale row per block.
// LDS sW: 128 rows x 128 shorts (256B = 16 chunks of 16B), chunk ^= (n&15).
__global__ __launch_bounds__(256) void dequant_wt(
    const int* __restrict__ packed, const float* __restrict__ gridv,
    const float* __restrict__ scales, const float* __restrict__ sv,
    unsigned short* __restrict__ Wt, int K, int N) {
  __shared__ float sGp[32];   // grid at stride 2 (bank-spread)
  __shared__ float sA[128];
  __shared__ unsigned short sW[128 * 128];  // 32KB

  int t = threadIdx.x;
  int n0 = blockIdx.x * 128;
  int k0 = blockIdx.y * 128;
  int g = k0 >> 7;
  if (t < 16) sGp[t * 2] = gridv[t];
  if (t < 128) sA[t] = scales[(size_t)g * N + n0 + t] * sv[n0 + t];
  __syncthreads();

  int c = t & 63;   // int-col -> n = 2c, 2c+1
  int w = t >> 6;   // k-quarter: rows k0 + w*32 + j
  size_t rs = (size_t)(N >> 1);
  const int* p = packed + (size_t)(k0 + w * 32) * rs + (n0 >> 1) + c;
  int pv[32];
#pragma unroll
  for (int j = 0; j < 32; ++j) pv[j] = p[(size_t)j * rs];

  float aLo = sA[2 * c], aHi = sA[2 * c + 1];
  unsigned int w0[16], w1[16];
#pragma unroll
  for (int q = 0; q < 16; ++q) {
    int va = pv[2 * q], vb = pv[2 * q + 1];
    w0[q] = (unsigned int)f2bf(sGp[(va & 15) * 2] * aLo) |
            ((unsigned int)f2bf(sGp[(vb & 15) * 2] * aLo) << 16);
    w1[q] = (unsigned int)f2bf(sGp[((va >> 4) & 15) * 2] * aHi) |
            ((unsigned int)f2bf(sGp[((vb >> 4) & 15) * 2] * aHi) << 16);
  }
  int nA = 2 * c, nB = 2 * c + 1;
#pragma unroll
  for (int q = 0; q < 4; ++q) {
    int ch = w * 4 + q;
    uint4 va; va.x = w0[4*q]; va.y = w0[4*q+1]; va.z = w0[4*q+2]; va.w = w0[4*q+3];
    uint4 vb; vb.x = w1[4*q]; vb.y = w1[4*q+1]; vb.z = w1[4*q+2]; vb.w = w1[4*q+3];
    *(uint4*)&sW[nA * 128 + ((ch ^ (nA & 15)) << 3)] = va;
    *(uint4*)&sW[nB * 128 + ((ch ^ (nB & 15)) << 3)] = vb;
  }
  __syncthreads();

  // out: 8 passes x (16 rows x 16 chunks); lanes 0-15 cover all 16 chunks.
#pragma unroll
  for (int ps = 0; ps < 8; ++ps) {
    int n = ps * 16 + (t >> 4);
    int ch = t & 15;
    uint4 v = *(const uint4*)&sW[n * 128 + ((ch ^ (n & 15)) << 3)];
    *(uint4*)(Wt + (size_t)(n0 + n) * K + k0 + ch * 8) = v;
  }
}

// ---------------------------------------------------------------------------
// C += x' @ Wt^T. BM=BN=128, BK=64, 4 waves (2x2) of 64x64, split-K.
// LDS swizzle: data for (row, chunk s) lives at chunk s^(row&7); achieved by
// permuting the global source chunk of each global_load_lds lane (linear dest).
#define BM 128
#define BN 128
#define BK 64
#define KSLICES 4

__global__ __launch_bounds__(256, 3) void gemm_xw(
    const unsigned short* __restrict__ A,  // [M][K] bf16 bits
    const unsigned short* __restrict__ B,  // [N][K] bf16 bits
    float* __restrict__ C, int M, int N, int K) {
  __shared__ unsigned short As[BM * BK];  // 16KB
  __shared__ unsigned short Bs[BN * BK];  // 16KB

  int t = threadIdx.x;
  int l = t & 63;
  int w = t >> 6;
  int wr = w >> 1, wc = w & 1;   // 2x2 waves, wave tile 64x64
  size_t m0 = (size_t)blockIdx.y * BM;
  size_t n0 = (size_t)blockIdx.x * BN;
  int kbeg = blockIdx.z * (K / KSLICES);
  int kend = kbeg + K / KSLICES;

  const unsigned short* Ag = A + m0 * K;
  const unsigned short* Bg = B + n0 * K;

  int srow = t >> 3;  // 0..31 staging row within round
  int sch = t & 7;    // dest chunk (LDS stays linear: dest short-idx = r*2048 + t*8)

  int lr = l & 15;
  int lh = l >> 4;    // 0..3

  f32x4 acc[4][4] = {};

  for (int k0 = kbeg; k0 < kend; k0 += BK) {
#pragma unroll
    for (int r = 0; r < 4; ++r) {
      int row = r * 32 + srow;
      int sc = (sch ^ (row & 7)) * 8;  // pre-swizzled source chunk
      gld16(Ag + (size_t)row * K + k0 + sc, &As[row * BK + sch * 8]);
    }
#pragma unroll
    for (int r = 0; r < 4; ++r) {
      int row = r * 32 + srow;
      int sc = (sch ^ (row & 7)) * 8;
      gld16(Bg + (size_t)row * K + k0 + sc, &Bs[row * BK + sch * 8]);
    }
    __syncthreads();

#pragma unroll
    for (int kh = 0; kh < 2; ++kh) {
      short8 a[4], b[4];
      int sk = kh * 4 + lh;
#pragma unroll
      for (int i = 0; i < 4; ++i) {
        int row = wr * 64 + i * 16 + lr;
        a[i] = *(const short8*)&As[row * BK + ((sk ^ (row & 7)) << 3)];
      }
#pragma unroll
      for (int j = 0; j < 4; ++j) {
        int row = wc * 64 + j * 16 + lr;
        b[j] = *(const short8*)&Bs[row * BK + ((sk ^ (row & 7)) << 3)];
      }
#pragma unroll
      for (int i = 0; i < 4; ++i)
#pragma unroll
        for (int j = 0; j < 4; ++j)
          acc[i][j] = __builtin_amdgcn_mfma_f32_16x16x32_bf16(a[i], b[j], acc[i][j], 0, 0, 0);
    }
    __syncthreads();
  }

  // Epilogue: C/D layout col=lane&15, row=(lane>>4)*4+r. Split-K -> atomicAdd.
#pragma unroll
  for (int i = 0; i < 4; ++i)
#pragma unroll
    for (int j = 0; j < 4; ++j) {
      size_t row = m0 + wr * 64 + i * 16 + lh * 4;
      size_t col = n0 + wc * 64 + j * 16 + lr;
#pragma unroll
      for (int r = 0; r < 4; ++r)
        atomicAdd(&C[(row + r) * N + col], acc[i][j][r]);
    }
}

// ---------------------------------------------------------------------------
extern "C" void kernel_launch(void* const* d_in, const int* in_sizes, int n_in,
                              void* d_out, int out_size, void* d_ws, size_t ws_size,
                              hipStream_t stream) {
  const float* x      = (const float*)d_in[0];
  const int*   packed = (const int*)d_in[1];
  const float* gridv  = (const float*)d_in[2];
  const float* scales = (const float*)d_in[3];
  const float* su     = (const float*)d_in[4];
  const float* sv     = (const float*)d_in[5];
  float* out = (float*)d_out;

  int K = in_sizes[4];
  int N = in_sizes[5];
  int M = in_sizes[0] / K;

  unsigned short* xp = (unsigned short*)d_ws;            // 8MB
  unsigned short* Wt = xp + (size_t)M * K;               // 128MB

  zero_out<<<1024, 256, 0, stream>>>((float4*)out, (M * N) / 4);
  convert_x_su<<<dim3(K / 2048, M), 256, 0, stream>>>(x, su, xp, K);
  dequant_wt<<<dim3(N / 128, K / 128), 256, 0, stream>>>(packed, gridv, scales, sv, Wt, K, N);
  gemm_xw<<<dim3(N / BN, M / BM, KSLICES), 256, 0, stream>>>(xp, Wt, out, M, N, K);
}

// Round 4
// 326.936 us; speedup vs baseline: 1.2780x; 1.1119x over previous
//
#include <hip/hip_runtime.h>

// TrellisLinear: out = (x * su) @ (grid[codes] * scales * sv)
// M=512, K=8192, N=8192, GROUP=128.
// Round 4 (= round 3 resubmit; bench infra timed out): dequant FUSED into GEMM.
//   1) zero_out      : d_out = 0 (split-K atomics accumulate into it)
//   2) convert_x_su  : x' = bf16(x*su) [M][K] in ws
//   3) gemm_fused    : per K-step, load packed codes -> registers, LUT+scale
//                      -> bf16 -> swizzled Bs in LDS; A via global_load_lds;
//                      MFMA 16x16x32; split-K=4 atomicAdd epilogue.

typedef __attribute__((ext_vector_type(8))) short short8;
typedef __attribute__((ext_vector_type(4))) float f32x4;

__device__ __forceinline__ unsigned short f2bf(float f) {
  unsigned int u = __builtin_bit_cast(unsigned int, f);
  u += 0x7FFFu + ((u >> 16) & 1u);
  return (unsigned short)(u >> 16);
}

__device__ __forceinline__ void gld16(const void* g, void* l) {
  __builtin_amdgcn_global_load_lds(
      (__attribute__((address_space(1))) void*)(g),
      (__attribute__((address_space(3))) void*)(l), 16, 0, 0);
}

// ---------------------------------------------------------------------------
__global__ __launch_bounds__(256) void zero_out(float4* __restrict__ p, int n4) {
  int i = blockIdx.x * 256 + threadIdx.x;
  int stride = gridDim.x * 256;
  for (; i < n4; i += stride) p[i] = float4{0.f, 0.f, 0.f, 0.f};
}

// ---------------------------------------------------------------------------
__global__ __launch_bounds__(256) void convert_x_su(
    const float* __restrict__ x, const float* __restrict__ su,
    unsigned short* __restrict__ xp, int K) {
  int k = blockIdx.x * 2048 + threadIdx.x * 8;
  size_t i = (size_t)blockIdx.y * K + k;
  float4 x0 = *(const float4*)(x + i);
  float4 x1 = *(const float4*)(x + i + 4);
  float4 s0 = *(const float4*)(su + k);
  float4 s1 = *(const float4*)(su + k + 4);
  unsigned int r0 = f2bf(x0.x * s0.x) | ((unsigned int)f2bf(x0.y * s0.y) << 16);
  unsigned int r1 = f2bf(x0.z * s0.z) | ((unsigned int)f2bf(x0.w * s0.w) << 16);
  unsigned int r2 = f2bf(x1.x * s1.x) | ((unsigned int)f2bf(x1.y * s1.y) << 16);
  unsigned int r3 = f2bf(x1.z * s1.z) | ((unsigned int)f2bf(x1.w * s1.w) << 16);
  uint4 o; o.x = r0; o.y = r1; o.z = r2; o.w = r3;
  *(uint4*)(xp + i) = o;
}

// ---------------------------------------------------------------------------
#define BM 128
#define BN 128
#define BK 64
#define KSLICES 4

__global__ __launch_bounds__(256, 3) void gemm_fused(
    const unsigned short* __restrict__ A,   // [M][K] bf16 bits (x*su)
    const int* __restrict__ packed,         // [K][N/2] byte codes in int32
    const float* __restrict__ gridv,        // [16]
    const float* __restrict__ scales,       // [K/128][N]
    const float* __restrict__ sv,           // [N]
    float* __restrict__ C, int M, int N, int K) {
  __shared__ unsigned short As[BM * BK];   // 16 KB
  __shared__ unsigned short Bs[BN * BK];   // 16 KB  [n][k], chunk ^= (n&7)
  __shared__ float sS[16 * 128];           // 8 KB   scales*sv for this K-slice
  __shared__ float sGp[32];                // grid duplicated at stride 2

  int t = threadIdx.x;
  int l = t & 63;
  int w = t >> 6;

  // T1 bijective XCD swizzle; work order m-fastest so the 4 M-blocks sharing
  // a packed panel land on the same XCD's L2.
  int nwg = gridDim.x;              // (N/BN)*(M/BM), divisible by 8
  int bid = blockIdx.x;
  int swz = (bid & 7) * (nwg >> 3) + (bid >> 3);
  int mblocks = M >> 7;
  int mb = swz % mblocks;
  int nb = swz / mblocks;
  size_t m0 = (size_t)mb * BM;
  size_t n0 = (size_t)nb * BN;
  int kbeg = blockIdx.y * (K / KSLICES);
  int kend = kbeg + K / KSLICES;

  // init LUT + scales
  if (t < 16) { float g = gridv[t]; sGp[t * 2] = g; sGp[t * 2 + 1] = g; }
  int g0 = kbeg >> 7;
  for (int i = t; i < 16 * 128; i += 256) {
    int g = i >> 7, n = i & 127;
    sS[i] = scales[(size_t)(g0 + g) * N + n0 + n] * sv[n0 + n];
  }
  __syncthreads();

  const unsigned short* Ag = A + m0 * K;
  size_t rs = (size_t)(N >> 1);
  int c = l;                       // packed int-col -> n = 2c, 2c+1
  int kq = w;                      // wave handles k-rows kq*16..kq*16+15
  const int* pbase = packed + (n0 >> 1) + c + (size_t)(kq * 16) * rs;
  const float* lut = &sGp[l & 1];  // parity-spread 32-bank LUT base

  int srow = t >> 3, sch = t & 7;
  int lr = l & 15, lh = l >> 4;
  int wr = w >> 1, wc = w & 1;
  int nA = 2 * c, nB = 2 * c + 1;

  f32x4 acc[4][4] = {};

  int pv[16];
  {
    const int* p = pbase + (size_t)kbeg * rs;
#pragma unroll
    for (int j = 0; j < 16; ++j) pv[j] = p[(size_t)j * rs];
  }

  for (int k0 = kbeg; k0 < kend; k0 += BK) {
    // ---- dequant pv -> Bs (Bs free: barrier at end of previous iteration)
    int gl = (k0 - kbeg) >> 7;
    float2 a2 = *(const float2*)&sS[gl * 128 + nA];  // aLo(n even), aHi(n odd)
#pragma unroll
    for (int q = 0; q < 2; ++q) {
      int ch = kq * 2 + q;
      uint4 va, vb;
      unsigned int* pa = (unsigned int*)&va;
      unsigned int* pbv = (unsigned int*)&vb;
#pragma unroll
      for (int d = 0; d < 4; ++d) {
        int v0 = pv[q * 8 + 2 * d], v1 = pv[q * 8 + 2 * d + 1];
        float w00 = lut[(v0 & 15) << 1];
        float w01 = lut[(v1 & 15) << 1];
        float w10 = lut[((v0 >> 4) & 15) << 1];
        float w11 = lut[((v1 >> 4) & 15) << 1];
        pa[d]  = (unsigned int)f2bf(w00 * a2.x) | ((unsigned int)f2bf(w01 * a2.x) << 16);
        pbv[d] = (unsigned int)f2bf(w10 * a2.y) | ((unsigned int)f2bf(w11 * a2.y) << 16);
      }
      *(uint4*)&Bs[nA * BK + ((ch ^ (nA & 7)) << 3)] = va;
      *(uint4*)&Bs[nB * BK + ((ch ^ (nB & 7)) << 3)] = vb;
    }

    // ---- A staging (async, linear dest, pre-swizzled source chunk)
#pragma unroll
    for (int r = 0; r < 4; ++r) {
      int row = r * 32 + srow;
      int sc = (sch ^ (row & 7)) * 8;
      gld16(Ag + (size_t)row * K + k0 + sc, &As[row * BK + sch * 8]);
    }
    __syncthreads();

    // ---- prefetch next K-step's codes; drains at the end-of-loop barrier,
    //      overlapping HBM/L3 latency with the MFMA phase.
    int pvn[16] = {};
    if (k0 + BK < kend) {
      const int* p = pbase + (size_t)(k0 + BK) * rs;
#pragma unroll
      for (int j = 0; j < 16; ++j) pvn[j] = p[(size_t)j * rs];
    }

    // ---- MFMA phase
#pragma unroll
    for (int kh = 0; kh < 2; ++kh) {
      short8 a[4], b[4];
      int sk = kh * 4 + lh;
#pragma unroll
      for (int i = 0; i < 4; ++i) {
        int row = wr * 64 + i * 16 + lr;
        a[i] = *(const short8*)&As[row * BK + ((sk ^ (row & 7)) << 3)];
      }
#pragma unroll
      for (int j = 0; j < 4; ++j) {
        int row = wc * 64 + j * 16 + lr;
        b[j] = *(const short8*)&Bs[row * BK + ((sk ^ (row & 7)) << 3)];
      }
#pragma unroll
      for (int i = 0; i < 4; ++i)
#pragma unroll
        for (int j = 0; j < 4; ++j)
          acc[i][j] = __builtin_amdgcn_mfma_f32_16x16x32_bf16(a[i], b[j], acc[i][j], 0, 0, 0);
    }
    __syncthreads();

#pragma unroll
    for (int j = 0; j < 16; ++j) pv[j] = pvn[j];
  }

  // ---- epilogue: C/D layout col=lane&15, row=(lane>>4)*4+r. split-K atomics.
#pragma unroll
  for (int i = 0; i < 4; ++i)
#pragma unroll
    for (int j = 0; j < 4; ++j) {
      size_t row = m0 + wr * 64 + i * 16 + lh * 4;
      size_t col = n0 + wc * 64 + j * 16 + lr;
#pragma unroll
      for (int r = 0; r < 4; ++r)
        atomicAdd(&C[(row + r) * N + col], acc[i][j][r]);
    }
}

// ---------------------------------------------------------------------------
extern "C" void kernel_launch(void* const* d_in, const int* in_sizes, int n_in,
                              void* d_out, int out_size, void* d_ws, size_t ws_size,
                              hipStream_t stream) {
  const float* x      = (const float*)d_in[0];
  const int*   packed = (const int*)d_in[1];
  const float* gridv  = (const float*)d_in[2];
  const float* scales = (const float*)d_in[3];
  const float* su     = (const float*)d_in[4];
  const float* sv     = (const float*)d_in[5];
  float* out = (float*)d_out;

  int K = in_sizes[4];
  int N = in_sizes[5];
  int M = in_sizes[0] / K;

  unsigned short* xp = (unsigned short*)d_ws;  // 8 MB

  zero_out<<<1024, 256, 0, stream>>>((float4*)out, (M * N) / 4);
  convert_x_su<<<dim3(K / 2048, M), 256, 0, stream>>>(x, su, xp, K);
  int nwg = (N / BN) * (M / BM);
  gemm_fused<<<dim3(nwg, KSLICES), 256, 0, stream>>>(xp, packed, gridv, scales, sv,
                                                     out, M, N, K);
}